// Round 5
// baseline (2134.081 us; speedup 1.0000x reference)
//
#include <hip/hip_runtime.h>

// Precoding GNN: 5 layers of z = Ws*x + Wm*(sum_k x) + Wk*(sum_m x), ReLU(1-4),
// then Frobenius power normalization per batch item.
// M=64 antennas, K=32 users, D=32 hidden, BS=1024.
//
// One 1024-thread block per batch item. Thread t owns node n1=t (state x1 in
// REGISTERS) and node n2=t+1024 (state in LDS, feature-major xs[d][t]).
//
// R1: default launch_bounds -> 64-VGPR budget -> spill -> 34 GB HBM.
// R2/R3/R4: every occupancy hint (launch_bounds(,4), waves_per_eu(4,4))
//   left VGPR_Count at 64 and ~3 GB scratch traffic. Conclusion: stop
//   fighting the allocator; restructure so 64 VGPRs is ENOUGH. Half the
//   per-thread state (node 2, 128 KiB/block) lives in LDS: gfx950 has
//   160 KiB/CU and we only used 26. Feature-major layout xs[d*1024+t] is
//   bank-conflict-free (consecutive lanes -> consecutive banks).

namespace {

constexpr int NTHREADS = 1024;
constexpr int LD = 33;   // row stride for small LDS matrices

typedef float vf32 __attribute__((ext_vector_type(32)));
typedef float vf16 __attribute__((ext_vector_type(16)));

template <int DIN, int DOUT, bool RELU>
__device__ __forceinline__ void gnn_layer_dev(
    vf32& x1,
    float* __restrict__ xs,     // [32*1024] node-2 state, xs[d*1024+t]
    const float* __restrict__ Wsg, const float* __restrict__ Wmg,
    const float* __restrict__ Wkg,
    float* __restrict__ Wm_l,   // [32*LD]
    float* __restrict__ Wk_l,   // [32*LD]
    float* __restrict__ Abuf,   // [64*LD]
    float* __restrict__ Bbuf,   // [32*LD]
    float* __restrict__ msgk,   // [32*LD]
    int t, int k, int m1, int m2, int lane)
{
    constexpr int CW = (DIN < 16) ? DIN : 16;   // butterfly chunk width

    // ---- phase 0: stage Wm/Wk to LDS, zero msgk ----
    for (int i = t; i < DOUT * DIN; i += NTHREADS) {
        const int h = i / DIN, d = i % DIN;
        Wm_l[h * LD + d] = Wmg[i];
        Wk_l[h * LD + d] = Wkg[i];
    }
    for (int i = t; i < 32 * LD; i += NTHREADS) msgk[i] = 0.0f;
    __syncthreads();

    // ---- phase 1a: msg_k pair-reduce + LDS atomics ----
    // Thread covers antennas {m1, m2}; lane^32 covers {m1^1, m2^1}; 16 waves
    // cover all 64 antennas via ds_add_f32 on msgk[k][d].
#pragma unroll
    for (int d = 0; d < DIN; ++d) {
        float s = x1[d] + xs[d * 1024 + t];
        s += __shfl_xor(s, 32);
        if (lane < 32) atomicAdd(&msgk[k * LD + d], s);
    }

    // ---- phase 1b: msg_m butterflies (16-feature chunks), fused A-dot ----
    // Butterfly is per-feature independent, so chunking keeps only 16 temps.
    {   // node 2 (LDS-resident), antenna m2
        float acc = 0.0f;
#pragma unroll
        for (int c = 0; c < DIN; c += CW) {
            vf16 mm;
#pragma unroll
            for (int j = 0; j < CW; ++j) mm[j] = xs[(c + j) * 1024 + t];
#pragma unroll
            for (int mask = 1; mask <= 16; mask <<= 1) {
#pragma unroll
                for (int j = 0; j < CW; ++j) mm[j] += __shfl_xor(mm[j], mask);
            }
            if (k < DOUT) {
#pragma unroll
                for (int j = 0; j < CW; ++j) acc += Wm_l[k * LD + c + j] * mm[j];
            }
        }
        if (k < DOUT) Abuf[m2 * LD + k] = acc;
    }
    {   // node 1 (register-resident), antenna m1
        float acc = 0.0f;
#pragma unroll
        for (int c = 0; c < DIN; c += CW) {
            vf16 mm;
#pragma unroll
            for (int j = 0; j < CW; ++j) mm[j] = x1[c + j];
#pragma unroll
            for (int mask = 1; mask <= 16; mask <<= 1) {
#pragma unroll
                for (int j = 0; j < CW; ++j) mm[j] += __shfl_xor(mm[j], mask);
            }
            if (k < DOUT) {
#pragma unroll
                for (int j = 0; j < CW; ++j) acc += Wm_l[k * LD + c + j] * mm[j];
            }
        }
        if (k < DOUT) Abuf[m1 * LD + k] = acc;
    }
    __syncthreads();

    // ---- phase 2: B[k][h] = Wk[h,:].msg_k (one dot per thread) ----
    if (t < 32 * DOUT) {
        const int kk = t / DOUT, hh = t % DOUT;
        float acc = 0.0f;
#pragma unroll
        for (int d = 0; d < DIN; ++d) acc += Wk_l[hh * LD + d] * msgk[kk * LD + d];
        Bbuf[kk * LD + hh] = acc;
    }
    __syncthreads();

    // ---- phase 3: z = Ws*x + A[m] + B[k] per node. Ws read from global with
    //      uniform constant offsets -> s_load into SGPRs (proven in R3).
    //      Node 2 first: stream old xs, then overwrite xs (thread-private
    //      column, no cross-thread hazard). Then node 1 in registers.
    {
        vf32 acc;
#pragma unroll
        for (int h = 0; h < DOUT; ++h) acc[h] = Abuf[m2 * LD + h] + Bbuf[k * LD + h];
#pragma unroll
        for (int d = 0; d < DIN; ++d) {
            const float xd = xs[d * 1024 + t];
#pragma unroll
            for (int h = 0; h < DOUT; ++h) acc[h] += Wsg[h * DIN + d] * xd;
        }
#pragma unroll
        for (int h = 0; h < DOUT; ++h)
            xs[h * 1024 + t] = RELU ? fmaxf(acc[h], 0.0f) : acc[h];
    }
    {
        vf32 acc;
#pragma unroll
        for (int h = 0; h < DOUT; ++h) acc[h] = Abuf[m1 * LD + h] + Bbuf[k * LD + h];
#pragma unroll
        for (int d = 0; d < DIN; ++d) {
            const float xd = x1[d];
#pragma unroll
            for (int h = 0; h < DOUT; ++h) acc[h] += Wsg[h * DIN + d] * xd;
        }
#pragma unroll
        for (int h = 0; h < DOUT; ++h)
            x1[h] = RELU ? fmaxf(acc[h], 0.0f) : acc[h];
    }
    __syncthreads();  // protect Wm/Wk/msgk/Abuf/Bbuf before next layer restages
}

__global__ void __launch_bounds__(NTHREADS)
__attribute__((amdgpu_waves_per_eu(4, 4)))
gnn_fused(
    const float* __restrict__ xg,
    const float* __restrict__ w1s, const float* __restrict__ w1m, const float* __restrict__ w1k,
    const float* __restrict__ w2s, const float* __restrict__ w2m, const float* __restrict__ w2k,
    const float* __restrict__ w3s, const float* __restrict__ w3m, const float* __restrict__ w3k,
    const float* __restrict__ w4s, const float* __restrict__ w4m, const float* __restrict__ w4k,
    const float* __restrict__ w5s, const float* __restrict__ w5m, const float* __restrict__ w5k,
    float* __restrict__ out)
{
    __shared__ float xs[32 * 1024];   // node-2 state, feature-major (128 KiB)
    __shared__ float Wm_l[32 * LD];
    __shared__ float Wk_l[32 * LD];
    __shared__ float Abuf[64 * LD];
    __shared__ float Bbuf[32 * LD];
    __shared__ float msgk[32 * LD];
    __shared__ float red[17];

    const int t = threadIdx.x;
    const int b = blockIdx.x;
    const int k = t & 31;
    const int m1 = t >> 5;
    const int m2 = m1 + 32;
    const int lane = t & 63;
    const int wave = t >> 6;

    vf32 x1;

    // input: (b, 64, 32, 2) -> node n covers floats [2n, 2n+1]
    const float2 a1 = *reinterpret_cast<const float2*>(xg + (size_t)b * 4096 + 2 * t);
    const float2 a2 = *reinterpret_cast<const float2*>(xg + (size_t)b * 4096 + 2048 + 2 * t);
    x1[0] = a1.x; x1[1] = a1.y;
    xs[0 * 1024 + t] = a2.x;
    xs[1 * 1024 + t] = a2.y;

    gnn_layer_dev<2, 32, true>(x1, xs, w1s, w1m, w1k,
                               Wm_l, Wk_l, Abuf, Bbuf, msgk, t, k, m1, m2, lane);
    gnn_layer_dev<32, 32, true>(x1, xs, w2s, w2m, w2k,
                                Wm_l, Wk_l, Abuf, Bbuf, msgk, t, k, m1, m2, lane);
    gnn_layer_dev<32, 32, true>(x1, xs, w3s, w3m, w3k,
                                Wm_l, Wk_l, Abuf, Bbuf, msgk, t, k, m1, m2, lane);
    gnn_layer_dev<32, 32, true>(x1, xs, w4s, w4m, w4k,
                                Wm_l, Wk_l, Abuf, Bbuf, msgk, t, k, m1, m2, lane);
    gnn_layer_dev<32, 2, false>(x1, xs, w5s, w5m, w5k,
                                Wm_l, Wk_l, Abuf, Bbuf, msgk, t, k, m1, m2, lane);

    // ---- pwr_norm: alpha = rsqrt(sum over all (m,k,c) of z^2) ----
    const float s2a = xs[0 * 1024 + t];
    const float s2b = xs[1 * 1024 + t];
    float p = x1[0] * x1[0] + x1[1] * x1[1] + s2a * s2a + s2b * s2b;
#pragma unroll
    for (int mask = 1; mask <= 32; mask <<= 1) p += __shfl_xor(p, mask);
    if (lane == 0) red[wave] = p;
    __syncthreads();
    if (t == 0) {
        float tot = 0.0f;
#pragma unroll
        for (int i = 0; i < 16; ++i) tot += red[i];
        red[16] = rsqrtf(tot);
    }
    __syncthreads();
    const float alpha = red[16];

    float2 o1, o2;
    o1.x = alpha * x1[0]; o1.y = alpha * x1[1];
    o2.x = alpha * s2a;   o2.y = alpha * s2b;
    *reinterpret_cast<float2*>(out + (size_t)b * 4096 + 2 * t) = o1;
    *reinterpret_cast<float2*>(out + (size_t)b * 4096 + 2048 + 2 * t) = o2;
}

}  // namespace

extern "C" void kernel_launch(void* const* d_in, const int* in_sizes, int n_in,
                              void* d_out, int out_size, void* d_ws, size_t ws_size,
                              hipStream_t stream) {
    const float* xg  = (const float*)d_in[0];
    const float* w1s = (const float*)d_in[1];
    const float* w1m = (const float*)d_in[2];
    const float* w1k = (const float*)d_in[3];
    const float* w2s = (const float*)d_in[4];
    const float* w2m = (const float*)d_in[5];
    const float* w2k = (const float*)d_in[6];
    const float* w3s = (const float*)d_in[7];
    const float* w3m = (const float*)d_in[8];
    const float* w3k = (const float*)d_in[9];
    const float* w4s = (const float*)d_in[10];
    const float* w4m = (const float*)d_in[11];
    const float* w4k = (const float*)d_in[12];
    const float* w5s = (const float*)d_in[13];
    const float* w5m = (const float*)d_in[14];
    const float* w5k = (const float*)d_in[15];
    float* out = (float*)d_out;

    hipLaunchKernelGGL(gnn_fused, dim3(1024), dim3(NTHREADS), 0, stream,
                       xg, w1s, w1m, w1k, w2s, w2m, w2k, w3s, w3m, w3k,
                       w4s, w4m, w4k, w5s, w5m, w5k, out);
}